// Round 10
// baseline (291.077 us; speedup 1.0000x reference)
//
#include <hip/hip_runtime.h>
#include <hip/hip_fp16.h>
#include <math.h>

#define N_NODES 50000
#define N_EDGES 1600000
#define DIM 128
#define HEADS 8
#define NEG_SLOPE 0.2f
#define BN_EPS 1e-5f

typedef _Float16 f16x8 __attribute__((ext_vector_type(8)));
typedef float f32x4 __attribute__((ext_vector_type(4)));

// ---------------------------------------------------------------------------
// K0: swizzle W (fp32 [K=128][N=128]) into MFMA B-fragment order, fp16.
// Also zero-inits bcur + BN accumulators (stream-ordered before their use).
// ---------------------------------------------------------------------------
__global__ void k_wprep(const float* __restrict__ W, __half* __restrict__ Wh,
                        int* __restrict__ bcur, float* __restrict__ gsums) {
    const int t = threadIdx.x;
    if (blockIdx.x == 0 && t < 256) bcur[t] = 0;
    if (blockIdx.x == 1 && t < 256) gsums[t] = 0.f;   // sums|sumsq contiguous
    const int tid = blockIdx.x * 256 + t;  // [0, 2048)
    const int g = tid >> 6;          // nt*4 + kt
    const int lane = tid & 63;
    const int nt = g >> 2, kt = g & 3;
    const int q = lane >> 4, n = lane & 15;
    #pragma unroll
    for (int j = 0; j < 8; ++j)
        Wh[(size_t)(g * 64 + lane) * 8 + j] =
            __float2half(W[(kt * 32 + q * 8 + j) * DIM + nt * 16 + n]);
}

// ---------------------------------------------------------------------------
// K1: xl = x @ W via MFMA 16x16x32 f16; fused per-head attention dots.
// One wave per 16 nodes (block = 4 waves = 64 nodes).
// C/D layout: col = lane&15, row = (lane>>4)*4 + reg  [m89 verified]
// ---------------------------------------------------------------------------
__global__ __launch_bounds__(256) void k_lin(const float* __restrict__ x,
                      const __half* __restrict__ Wh, const float* __restrict__ att_s,
                      const float* __restrict__ att_d, __half* __restrict__ xlh,
                      float* __restrict__ a_src, float* __restrict__ a_dst) {
    const int wave = threadIdx.x >> 6;
    const int lane = threadIdx.x & 63;
    const int q = lane >> 4, n = lane & 15;
    const int nb = (blockIdx.x * 4 + wave) * 16;

    const int rowA = min(nb + n, N_NODES - 1);
    const float* xr = x + (size_t)rowA * DIM;
    f16x8 a[4];
    #pragma unroll
    for (int kt = 0; kt < 4; ++kt) {
        const float4 p0 = *(const float4*)(xr + kt * 32 + q * 8);
        const float4 p1 = *(const float4*)(xr + kt * 32 + q * 8 + 4);
        a[kt][0] = (_Float16)p0.x; a[kt][1] = (_Float16)p0.y;
        a[kt][2] = (_Float16)p0.z; a[kt][3] = (_Float16)p0.w;
        a[kt][4] = (_Float16)p1.x; a[kt][5] = (_Float16)p1.y;
        a[kt][6] = (_Float16)p1.z; a[kt][7] = (_Float16)p1.w;
    }

    f32x4 acc[8];
    #pragma unroll
    for (int nt = 0; nt < 8; ++nt) acc[nt] = (f32x4){0.f, 0.f, 0.f, 0.f};

    const f16x8* wb = (const f16x8*)Wh;
    #pragma unroll
    for (int nt = 0; nt < 8; ++nt) {
        #pragma unroll
        for (int kt = 0; kt < 4; ++kt) {
            const f16x8 b = wb[(nt * 4 + kt) * 64 + lane];
            acc[nt] = __builtin_amdgcn_mfma_f32_16x16x32_f16(a[kt], b, acc[nt], 0, 0, 0);
        }
    }

    const int r0 = nb + q * 4;
    #pragma unroll
    for (int nt = 0; nt < 8; ++nt) {
        const float as = att_s[nt * 16 + n];
        const float ad = att_d[nt * 16 + n];
        #pragma unroll
        for (int r = 0; r < 4; ++r) {
            const int row = r0 + r;
            const float v = acc[nt][r];
            float s = v * as;
            float d = v * ad;
            #pragma unroll
            for (int off = 8; off; off >>= 1) {
                s += __shfl_xor(s, off, 16);
                d += __shfl_xor(d, off, 16);
            }
            if (row < N_NODES) {
                xlh[(size_t)row * DIM + nt * 16 + n] = __float2half(v);
                if (n == 0) {
                    a_src[row * HEADS + nt] = s;
                    a_dst[row * HEADS + nt] = d;
                }
            }
        }
    }
}

// ---------------------------------------------------------------------------
// Binned CSR build with fixed-capacity bucket segments (no global scan).
// bucket b = dst>>8; segment base = b*SEGCAP. 1024-thread blocks.
// ---------------------------------------------------------------------------
#define NBUCK 196
#define SEGCAP 12288
#define CHUNK 8192
#define NB_A ((N_EDGES + CHUNK - 1) / CHUNK)   // 196

__global__ __launch_bounds__(1024) void k_binA(const int* __restrict__ ei,
                                               int* __restrict__ bcur,
                                               unsigned int* __restrict__ pairs) {
    __shared__ int hist[NBUCK], excl[NBUCK], gbase[NBUCK], cnt2[NBUCK];
    __shared__ int sc[256];
    __shared__ unsigned int buf[CHUNK];     // 32 KB
    const int t = threadIdx.x;
    const int base = blockIdx.x * CHUNK;
    const int cnt = min(CHUNK, N_EDGES - base);   // always multiple of 4

    for (int j = t; j < NBUCK; j += 1024) { hist[j] = 0; cnt2[j] = 0; }
    __syncthreads();
    for (int i = t * 4; i < cnt; i += 4096) {
        const int4 dv = *(const int4*)(ei + N_EDGES + base + i);
        atomicAdd(&hist[dv.x >> 8], 1);
        atomicAdd(&hist[dv.y >> 8], 1);
        atomicAdd(&hist[dv.z >> 8], 1);
        atomicAdd(&hist[dv.w >> 8], 1);
    }
    __syncthreads();
    if (t < 256) sc[t] = (t < NBUCK) ? hist[t] : 0;
    __syncthreads();
    for (int d = 1; d < 256; d <<= 1) {
        int xo = 0;
        if (t < 256 && t >= d) xo = sc[t - d];
        __syncthreads();
        if (t < 256) sc[t] += xo;
        __syncthreads();
    }
    if (t < NBUCK) {
        excl[t] = sc[t] - hist[t];
        gbase[t] = t * SEGCAP + atomicAdd(&bcur[t], hist[t]);
    }
    __syncthreads();
    for (int i = t * 4; i < cnt; i += 4096) {
        const int4 sv = *(const int4*)(ei + base + i);
        const int4 dv = *(const int4*)(ei + N_EDGES + base + i);
        const int ss[4] = {sv.x, sv.y, sv.z, sv.w};
        const int dd[4] = {dv.x, dv.y, dv.z, dv.w};
        #pragma unroll
        for (int k = 0; k < 4; ++k) {
            const int b = dd[k] >> 8;
            const int r = atomicAdd(&cnt2[b], 1);
            buf[excl[b] + r] = (unsigned int)ss[k] | ((unsigned int)(dd[k] & 255) << 16)
                             | ((unsigned int)b << 24);
        }
    }
    __syncthreads();
    for (int i = t; i < cnt; i += 1024) {
        const unsigned int u = buf[i];
        const int b = u >> 24;
        pairs[gbase[b] + (i - excl[b])] = u & 0xFFFFFF;
    }
}

// Phase B: one block per bucket; LDS counting sort by dst&255. Node segment
// starts padded to EVEN csr indices. Emits csr (ushort) in-place into pairs
// + per-node [lo,hi) ranges.
__global__ __launch_bounds__(1024) void k_binB(const unsigned int* __restrict__ pairs,
                                               const int* __restrict__ bcur,
                                               unsigned short* __restrict__ csr,
                                               int2* __restrict__ nrange) {
    __shared__ int hist[256], eh[256], excl[256], cnt2[256];
    __shared__ int plen;
    __shared__ unsigned short out[SEGCAP];  // 24 KB
    const int t = threadIdx.x;
    const int b = blockIdx.x;
    const int lo = b * SEGCAP;              // u32 index into pairs
    const int cnt = bcur[b];

    if (t < 256) { hist[t] = 0; cnt2[t] = 0; }
    __syncthreads();
    for (int i = t; i < cnt; i += 1024)
        atomicAdd(&hist[pairs[lo + i] >> 16], 1);
    __syncthreads();
    if (t < 256) { eh[t] = (hist[t] + 1) & ~1; excl[t] = eh[t]; }
    __syncthreads();
    for (int d = 1; d < 256; d <<= 1) {
        int xo = 0;
        if (t < 256 && t >= d) xo = excl[t - d];
        __syncthreads();
        if (t < 256) excl[t] += xo;
        __syncthreads();
    }
    if (t < 256) excl[t] -= eh[t];          // exclusive padded starts (even)
    if (t == 255) plen = excl[255] + eh[255];
    __syncthreads();
    for (int i = t; i < cnt; i += 1024) {
        const unsigned int u = pairs[lo + i];
        const int dl = u >> 16;
        const int r = atomicAdd(&cnt2[dl], 1);
        out[excl[dl] + r] = (unsigned short)(u & 0xFFFF);
    }
    __syncthreads();
    const int pl = plen;                    // <= cnt + 256 <= SEGCAP
    for (int i = t; i < pl; i += 1024)
        csr[2 * lo + i] = out[i];           // pad gaps: garbage, never read
    if (t < 256) {
        const int node = (b << 8) + t;
        if (node < N_NODES) {
            int2 rg;
            rg.x = 2 * lo + excl[t];
            rg.y = rg.x + hist[t];
            nrange[node] = rg;
        }
    }
}

// ---------------------------------------------------------------------------
// K3: fused softmax + aggregation + BN partials. aggr2's proven structure:
// ONE node per wave, 12500 blocks x 4 waves, 8 independent ushort csr loads
// per batch (max MLP). BN: 4 LDS atomics/lane -> non-atomic 256-float
// partial row per block (no global atomics).
// ---------------------------------------------------------------------------
#define AGG_NB (N_NODES / 4)   // 12500

__global__ __launch_bounds__(256) void k_aggr5(const int2* __restrict__ nrange,
                        const unsigned short* __restrict__ csr,
                        const float* __restrict__ a_src, const float* __restrict__ a_dst,
                        const __half* __restrict__ xlh, const float* __restrict__ bias,
                        float* __restrict__ y, float* __restrict__ partials) {
    __shared__ float ch[256];               // [sums(128) | sumsq(128)]
    const int t = threadIdx.x;
    const int d = blockIdx.x * 4 + (t >> 6);
    const int lane = t & 63;
    const int c2 = lane << 1;
    const int h = lane >> 3;
    ch[t] = 0.f;
    __syncthreads();

    const int2 rg = nrange[d];
    const int lo = rg.x, hi = rg.y;
    const float ad = a_dst[d * HEADS + h];
    float acc0 = 0.f, acc1 = 0.f, dsum = 0.f;
    int i = lo;
    for (; i + 8 <= hi; i += 8) {
        int s[8];
        float e[8];
        __half2 xv[8];
        #pragma unroll
        for (int j = 0; j < 8; ++j) s[j] = csr[i + j];
        #pragma unroll
        for (int j = 0; j < 8; ++j) e[j] = a_src[s[j] * HEADS + h] + ad;
        #pragma unroll
        for (int j = 0; j < 8; ++j)
            xv[j] = *(const __half2*)(xlh + (size_t)s[j] * DIM + c2);
        #pragma unroll
        for (int j = 0; j < 8; ++j) {
            const float w = __expf(fmaxf(e[j], NEG_SLOPE * e[j]));
            const float2 f = __half22float2(xv[j]);
            acc0 = fmaf(w, f.x, acc0);
            acc1 = fmaf(w, f.y, acc1);
            dsum += w;
        }
    }
    for (; i < hi; ++i) {
        const int s = csr[i];
        const float e = a_src[s * HEADS + h] + ad;
        const __half2 xv = *(const __half2*)(xlh + (size_t)s * DIM + c2);
        const float w = __expf(fmaxf(e, NEG_SLOPE * e));
        const float2 f = __half22float2(xv);
        acc0 = fmaf(w, f.x, acc0); acc1 = fmaf(w, f.y, acc1); dsum += w;
    }
    const float inv = 1.f / (dsum + 1e-16f);
    const float o0 = acc0 * inv, o1 = acc1 * inv;
    float2 o; o.x = o0; o.y = o1;
    *(float2*)(y + (size_t)d * DIM + c2) = o;

    const float h0 = o0 + bias[c2], h1 = o1 + bias[c2 + 1];
    atomicAdd(&ch[c2], h0);
    atomicAdd(&ch[c2 + 1], h1);
    atomicAdd(&ch[DIM + c2], h0 * h0);
    atomicAdd(&ch[DIM + c2 + 1], h1 * h1);
    __syncthreads();
    partials[(size_t)blockIdx.x * 256 + t] = ch[t];   // non-atomic row
}

// reduce 12500 partial rows -> gsums = [sums(128) | sumsq(128)]
#define NRED 100
__global__ void k_red(const float* __restrict__ partials, float* __restrict__ gsums) {
    const int t = threadIdx.x;
    float v = 0.f;
    for (int r = blockIdx.x; r < AGG_NB; r += NRED)
        v += partials[(size_t)r * 256 + t];
    atomicAdd(&gsums[t], v);
}

// ---------------------------------------------------------------------------
// K4: y = x + relu((y + bias - mean) * rsqrt(var+eps) * gamma + beta)
// BN fold computed inline per thread (sums/sumsq L2-resident).
// ---------------------------------------------------------------------------
__global__ void k_final(float* __restrict__ y, const float* __restrict__ x,
                        const float* __restrict__ sums, const float* __restrict__ sumsq,
                        const float* __restrict__ gamma, const float* __restrict__ beta,
                        const float* __restrict__ bias) {
    const int q = blockIdx.x * blockDim.x + threadIdx.x;
    const int cq = q & (DIM / 4 - 1);
    const float4 sm = ((const float4*)sums)[cq];
    const float4 sq = ((const float4*)sumsq)[cq];
    const float4 gm = ((const float4*)gamma)[cq];
    const float4 bt = ((const float4*)beta)[cq];
    const float4 bs = ((const float4*)bias)[cq];
    float4 v = ((const float4*)y)[q];
    const float4 xv = ((const float4*)x)[q];
    const float inv_n = 1.f / (float)N_NODES;
#define BNC(c) { const float mean = sm.c * inv_n;                         \
                 const float var = sq.c * inv_n - mean * mean;            \
                 const float sc = rsqrtf(var + BN_EPS) * gm.c;            \
                 const float sh = bt.c + (bs.c - mean) * sc;              \
                 v.c = xv.c + fmaxf(v.c * sc + sh, 0.f); }
    BNC(x) BNC(y) BNC(z) BNC(w)
#undef BNC
    ((float4*)y)[q] = v;
}

extern "C" void kernel_launch(void* const* d_in, const int* in_sizes, int n_in,
                              void* d_out, int out_size, void* d_ws, size_t ws_size,
                              hipStream_t stream) {
    const float* x     = (const float*)d_in[0];
    const int*   ei    = (const int*)  d_in[1];
    const float* W     = (const float*)d_in[2];
    const float* att_s = (const float*)d_in[3];
    const float* att_d = (const float*)d_in[4];
    const float* bias  = (const float*)d_in[5];
    const float* gamma = (const float*)d_in[6];
    const float* beta  = (const float*)d_in[7];
    float* y = (float*)d_out;

    // workspace layout
    __half* xlh  = (__half*)d_ws;                          // 6,400,000 h (12.8 MB)
    float* a_src = (float*)(xlh + (size_t)N_NODES * DIM);  // 400,000 f
    float* a_dst = a_src + (size_t)N_NODES * HEADS;        // 400,000 f
    float* sums  = a_dst + (size_t)N_NODES * HEADS;        // 128 f
    float* sumsq = sums  + DIM;                            // 128 f
    int*   bcur  = (int*)(sumsq + DIM);                    // 256 i
    int2*  nrange = (int2*)(bcur + 256);                   // 50,000 int2
    __half* Wh   = (__half*)(nrange + N_NODES);            // 16,384 h (32 KB)
    unsigned int* pairs = (unsigned int*)(Wh + 16384);     // 196*12288 u32 (9.6 MB)
    unsigned short* csr = (unsigned short*)pairs;          // aliases pairs (in-place)
    float* partials = (float*)(pairs + (size_t)NBUCK * SEGCAP); // 12500*256 f (12.8 MB)

    k_wprep<<<8, 256, 0, stream>>>(W, Wh, bcur, sums);
    k_lin<<<(N_NODES + 63) / 64, 256, 0, stream>>>(x, Wh, att_s, att_d, xlh, a_src, a_dst);
    k_binA<<<NB_A, 1024, 0, stream>>>(ei, bcur, pairs);
    k_binB<<<NBUCK, 1024, 0, stream>>>(pairs, bcur, csr, nrange);
    k_aggr5<<<AGG_NB, 256, 0, stream>>>(nrange, csr, a_src, a_dst, xlh, bias, y, partials);
    k_red<<<NRED, 256, 0, stream>>>(partials, sums);
    k_final<<<(size_t)N_NODES * DIM / 4 / 256, 256, 0, stream>>>(y, x, sums, sumsq,
                                                                 gamma, beta, bias);
}

// Round 11
// 239.692 us; speedup vs baseline: 1.2144x; 1.2144x over previous
//
#include <hip/hip_runtime.h>
#include <hip/hip_fp16.h>
#include <math.h>

#define N_NODES 50000
#define N_EDGES 1600000
#define DIM 128
#define HEADS 8
#define NEG_SLOPE 0.2f
#define BN_EPS 1e-5f

typedef _Float16 f16x8 __attribute__((ext_vector_type(8)));
typedef float f32x4 __attribute__((ext_vector_type(4)));

// ---------------------------------------------------------------------------
// K0: swizzle W (fp32 [K=128][N=128]) into MFMA B-fragment order, fp16.
// Also zero-inits bcur + BN accumulators (stream-ordered before their use).
// ---------------------------------------------------------------------------
__global__ void k_wprep(const float* __restrict__ W, __half* __restrict__ Wh,
                        int* __restrict__ bcur, float* __restrict__ gsums) {
    const int t = threadIdx.x;
    if (blockIdx.x == 0 && t < 256) bcur[t] = 0;
    if (blockIdx.x == 1 && t < 256) gsums[t] = 0.f;   // sums|sumsq contiguous
    const int tid = blockIdx.x * 256 + t;  // [0, 2048)
    const int g = tid >> 6;          // nt*4 + kt
    const int lane = tid & 63;
    const int nt = g >> 2, kt = g & 3;
    const int q = lane >> 4, n = lane & 15;
    #pragma unroll
    for (int j = 0; j < 8; ++j)
        Wh[(size_t)(g * 64 + lane) * 8 + j] =
            __float2half(W[(kt * 32 + q * 8 + j) * DIM + nt * 16 + n]);
}

// ---------------------------------------------------------------------------
// K1: xl = x @ W via MFMA 16x16x32 f16; fused per-head attention dots.
// One wave per 16 nodes (block = 4 waves = 64 nodes).
// C/D layout: col = lane&15, row = (lane>>4)*4 + reg  [m89 verified]
// ---------------------------------------------------------------------------
__global__ __launch_bounds__(256) void k_lin(const float* __restrict__ x,
                      const __half* __restrict__ Wh, const float* __restrict__ att_s,
                      const float* __restrict__ att_d, __half* __restrict__ xlh,
                      float* __restrict__ a_src, float* __restrict__ a_dst) {
    const int wave = threadIdx.x >> 6;
    const int lane = threadIdx.x & 63;
    const int q = lane >> 4, n = lane & 15;
    const int nb = (blockIdx.x * 4 + wave) * 16;

    const int rowA = min(nb + n, N_NODES - 1);
    const float* xr = x + (size_t)rowA * DIM;
    f16x8 a[4];
    #pragma unroll
    for (int kt = 0; kt < 4; ++kt) {
        const float4 p0 = *(const float4*)(xr + kt * 32 + q * 8);
        const float4 p1 = *(const float4*)(xr + kt * 32 + q * 8 + 4);
        a[kt][0] = (_Float16)p0.x; a[kt][1] = (_Float16)p0.y;
        a[kt][2] = (_Float16)p0.z; a[kt][3] = (_Float16)p0.w;
        a[kt][4] = (_Float16)p1.x; a[kt][5] = (_Float16)p1.y;
        a[kt][6] = (_Float16)p1.z; a[kt][7] = (_Float16)p1.w;
    }

    f32x4 acc[8];
    #pragma unroll
    for (int nt = 0; nt < 8; ++nt) acc[nt] = (f32x4){0.f, 0.f, 0.f, 0.f};

    const f16x8* wb = (const f16x8*)Wh;
    #pragma unroll
    for (int nt = 0; nt < 8; ++nt) {
        #pragma unroll
        for (int kt = 0; kt < 4; ++kt) {
            const f16x8 b = wb[(nt * 4 + kt) * 64 + lane];
            acc[nt] = __builtin_amdgcn_mfma_f32_16x16x32_f16(a[kt], b, acc[nt], 0, 0, 0);
        }
    }

    const int r0 = nb + q * 4;
    #pragma unroll
    for (int nt = 0; nt < 8; ++nt) {
        const float as = att_s[nt * 16 + n];
        const float ad = att_d[nt * 16 + n];
        #pragma unroll
        for (int r = 0; r < 4; ++r) {
            const int row = r0 + r;
            const float v = acc[nt][r];
            float s = v * as;
            float d = v * ad;
            #pragma unroll
            for (int off = 8; off; off >>= 1) {
                s += __shfl_xor(s, off, 16);
                d += __shfl_xor(d, off, 16);
            }
            if (row < N_NODES) {
                xlh[(size_t)row * DIM + nt * 16 + n] = __float2half(v);
                if (n == 0) {
                    a_src[row * HEADS + nt] = s;
                    a_dst[row * HEADS + nt] = d;
                }
            }
        }
    }
}

// ---------------------------------------------------------------------------
// Binned CSR build with fixed-capacity bucket segments (no global scan).
// bucket b = dst>>8; segment base = b*SEGCAP. 1024-thread blocks.
// ---------------------------------------------------------------------------
#define NBUCK 196
#define SEGCAP 12288
#define CHUNK 8192
#define NB_A ((N_EDGES + CHUNK - 1) / CHUNK)   // 196

__global__ __launch_bounds__(1024) void k_binA(const int* __restrict__ ei,
                                               int* __restrict__ bcur,
                                               unsigned int* __restrict__ pairs) {
    __shared__ int hist[NBUCK], excl[NBUCK], gbase[NBUCK], cnt2[NBUCK];
    __shared__ int sc[256];
    __shared__ unsigned int buf[CHUNK];     // 32 KB
    const int t = threadIdx.x;
    const int base = blockIdx.x * CHUNK;
    const int cnt = min(CHUNK, N_EDGES - base);   // always multiple of 4

    for (int j = t; j < NBUCK; j += 1024) { hist[j] = 0; cnt2[j] = 0; }
    __syncthreads();
    for (int i = t * 4; i < cnt; i += 4096) {
        const int4 dv = *(const int4*)(ei + N_EDGES + base + i);
        atomicAdd(&hist[dv.x >> 8], 1);
        atomicAdd(&hist[dv.y >> 8], 1);
        atomicAdd(&hist[dv.z >> 8], 1);
        atomicAdd(&hist[dv.w >> 8], 1);
    }
    __syncthreads();
    if (t < 256) sc[t] = (t < NBUCK) ? hist[t] : 0;
    __syncthreads();
    for (int d = 1; d < 256; d <<= 1) {
        int xo = 0;
        if (t < 256 && t >= d) xo = sc[t - d];
        __syncthreads();
        if (t < 256) sc[t] += xo;
        __syncthreads();
    }
    if (t < NBUCK) {
        excl[t] = sc[t] - hist[t];
        gbase[t] = t * SEGCAP + atomicAdd(&bcur[t], hist[t]);
    }
    __syncthreads();
    for (int i = t * 4; i < cnt; i += 4096) {
        const int4 sv = *(const int4*)(ei + base + i);
        const int4 dv = *(const int4*)(ei + N_EDGES + base + i);
        const int ss[4] = {sv.x, sv.y, sv.z, sv.w};
        const int dd[4] = {dv.x, dv.y, dv.z, dv.w};
        #pragma unroll
        for (int k = 0; k < 4; ++k) {
            const int b = dd[k] >> 8;
            const int r = atomicAdd(&cnt2[b], 1);
            buf[excl[b] + r] = (unsigned int)ss[k] | ((unsigned int)(dd[k] & 255) << 16)
                             | ((unsigned int)b << 24);
        }
    }
    __syncthreads();
    for (int i = t; i < cnt; i += 1024) {
        const unsigned int u = buf[i];
        const int b = u >> 24;
        pairs[gbase[b] + (i - excl[b])] = u & 0xFFFFFF;
    }
}

// Phase B: one block per bucket; LDS counting sort by dst&255. Node segment
// starts padded to EVEN csr indices. Emits csr (ushort) in-place into pairs
// + per-node [lo,hi) ranges.
__global__ __launch_bounds__(1024) void k_binB(const unsigned int* __restrict__ pairs,
                                               const int* __restrict__ bcur,
                                               unsigned short* __restrict__ csr,
                                               int2* __restrict__ nrange) {
    __shared__ int hist[256], eh[256], excl[256], cnt2[256];
    __shared__ int plen;
    __shared__ unsigned short out[SEGCAP];  // 24 KB
    const int t = threadIdx.x;
    const int b = blockIdx.x;
    const int lo = b * SEGCAP;              // u32 index into pairs
    const int cnt = bcur[b];

    if (t < 256) { hist[t] = 0; cnt2[t] = 0; }
    __syncthreads();
    for (int i = t; i < cnt; i += 1024)
        atomicAdd(&hist[pairs[lo + i] >> 16], 1);
    __syncthreads();
    if (t < 256) { eh[t] = (hist[t] + 1) & ~1; excl[t] = eh[t]; }
    __syncthreads();
    for (int d = 1; d < 256; d <<= 1) {
        int xo = 0;
        if (t < 256 && t >= d) xo = excl[t - d];
        __syncthreads();
        if (t < 256) excl[t] += xo;
        __syncthreads();
    }
    if (t < 256) excl[t] -= eh[t];          // exclusive padded starts (even)
    if (t == 255) plen = excl[255] + eh[255];
    __syncthreads();
    for (int i = t; i < cnt; i += 1024) {
        const unsigned int u = pairs[lo + i];
        const int dl = u >> 16;
        const int r = atomicAdd(&cnt2[dl], 1);
        out[excl[dl] + r] = (unsigned short)(u & 0xFFFF);
    }
    __syncthreads();
    const int pl = plen;                    // <= cnt + 256 <= SEGCAP
    for (int i = t; i < pl; i += 1024)
        csr[2 * lo + i] = out[i];           // pad gaps: garbage, never read
    if (t < 256) {
        const int node = (b << 8) + t;
        if (node < N_NODES) {
            int2 rg;
            rg.x = 2 * lo + excl[t];
            rg.y = rg.x + hist[t];
            nrange[node] = rg;
        }
    }
}

// ---------------------------------------------------------------------------
// K3: fused softmax + aggregation. R6's proven 67us structure, untouched:
// ONE node per wave, 12500 blocks x 4 waves, 8 independent ushort csr loads,
// no LDS, no barriers, no atomics. Writes y only.
// ---------------------------------------------------------------------------
#define AGG_NB (N_NODES / 4)   // 12500

__global__ void k_aggr6(const int2* __restrict__ nrange,
                        const unsigned short* __restrict__ csr,
                        const float* __restrict__ a_src, const float* __restrict__ a_dst,
                        const __half* __restrict__ xlh, float* __restrict__ y) {
    const int d = blockIdx.x * 4 + (threadIdx.x >> 6);
    const int lane = threadIdx.x & 63;
    const int c2 = lane << 1;
    const int h = lane >> 3;
    const int2 rg = nrange[d];
    const int lo = rg.x, hi = rg.y;
    const float ad = a_dst[d * HEADS + h];
    float acc0 = 0.f, acc1 = 0.f, dsum = 0.f;
    int i = lo;
    for (; i + 8 <= hi; i += 8) {
        int s[8];
        float e[8];
        __half2 xv[8];
        #pragma unroll
        for (int j = 0; j < 8; ++j) s[j] = csr[i + j];
        #pragma unroll
        for (int j = 0; j < 8; ++j) e[j] = a_src[s[j] * HEADS + h] + ad;
        #pragma unroll
        for (int j = 0; j < 8; ++j)
            xv[j] = *(const __half2*)(xlh + (size_t)s[j] * DIM + c2);
        #pragma unroll
        for (int j = 0; j < 8; ++j) {
            const float w = __expf(fmaxf(e[j], NEG_SLOPE * e[j]));
            const float2 f = __half22float2(xv[j]);
            acc0 = fmaf(w, f.x, acc0);
            acc1 = fmaf(w, f.y, acc1);
            dsum += w;
        }
    }
    for (; i < hi; ++i) {
        const int s = csr[i];
        const float e = a_src[s * HEADS + h] + ad;
        const __half2 xv = *(const __half2*)(xlh + (size_t)s * DIM + c2);
        const float w = __expf(fmaxf(e, NEG_SLOPE * e));
        const float2 f = __half22float2(xv);
        acc0 = fmaf(w, f.x, acc0); acc1 = fmaf(w, f.y, acc1); dsum += w;
    }
    const float inv = 1.f / (dsum + 1e-16f);
    float2 o; o.x = acc0 * inv; o.y = acc1 * inv;
    *(float2*)(y + (size_t)d * DIM + c2) = o;
}

// ---------------------------------------------------------------------------
// BN stats over h = y + bias (R6-proven shape: 512 blocks x 128 threads)
// ---------------------------------------------------------------------------
__global__ void k_stats(const float* __restrict__ y, const float* __restrict__ bias,
                        float* __restrict__ gsums) {
    const int c = threadIdx.x;
    const float b = bias[c];
    float s = 0.f, ss = 0.f;
    for (int n = blockIdx.x; n < N_NODES; n += gridDim.x) {
        const float h = y[n * DIM + c] + b;
        s += h;
        ss += h * h;
    }
    atomicAdd(&gsums[c], s);
    atomicAdd(&gsums[DIM + c], ss);
}

// ---------------------------------------------------------------------------
// K4: y = x + relu((y + bias - mean) * rsqrt(var+eps) * gamma + beta)
// BN fold computed inline per thread (sums/sumsq L2-resident).
// ---------------------------------------------------------------------------
__global__ void k_final(float* __restrict__ y, const float* __restrict__ x,
                        const float* __restrict__ sums, const float* __restrict__ sumsq,
                        const float* __restrict__ gamma, const float* __restrict__ beta,
                        const float* __restrict__ bias) {
    const int q = blockIdx.x * blockDim.x + threadIdx.x;
    const int cq = q & (DIM / 4 - 1);
    const float4 sm = ((const float4*)sums)[cq];
    const float4 sq = ((const float4*)sumsq)[cq];
    const float4 gm = ((const float4*)gamma)[cq];
    const float4 bt = ((const float4*)beta)[cq];
    const float4 bs = ((const float4*)bias)[cq];
    float4 v = ((const float4*)y)[q];
    const float4 xv = ((const float4*)x)[q];
    const float inv_n = 1.f / (float)N_NODES;
#define BNC(c) { const float mean = sm.c * inv_n;                         \
                 const float var = sq.c * inv_n - mean * mean;            \
                 const float sc = rsqrtf(var + BN_EPS) * gm.c;            \
                 const float sh = bt.c + (bs.c - mean) * sc;              \
                 v.c = xv.c + fmaxf(v.c * sc + sh, 0.f); }
    BNC(x) BNC(y) BNC(z) BNC(w)
#undef BNC
    ((float4*)y)[q] = v;
}

extern "C" void kernel_launch(void* const* d_in, const int* in_sizes, int n_in,
                              void* d_out, int out_size, void* d_ws, size_t ws_size,
                              hipStream_t stream) {
    const float* x     = (const float*)d_in[0];
    const int*   ei    = (const int*)  d_in[1];
    const float* W     = (const float*)d_in[2];
    const float* att_s = (const float*)d_in[3];
    const float* att_d = (const float*)d_in[4];
    const float* bias  = (const float*)d_in[5];
    const float* gamma = (const float*)d_in[6];
    const float* beta  = (const float*)d_in[7];
    float* y = (float*)d_out;

    // workspace layout
    __half* xlh  = (__half*)d_ws;                          // 6,400,000 h (12.8 MB)
    float* a_src = (float*)(xlh + (size_t)N_NODES * DIM);  // 400,000 f
    float* a_dst = a_src + (size_t)N_NODES * HEADS;        // 400,000 f
    float* sums  = a_dst + (size_t)N_NODES * HEADS;        // 128 f
    float* sumsq = sums  + DIM;                            // 128 f
    int*   bcur  = (int*)(sumsq + DIM);                    // 256 i
    int2*  nrange = (int2*)(bcur + 256);                   // 50,000 int2
    __half* Wh   = (__half*)(nrange + N_NODES);            // 16,384 h (32 KB)
    unsigned int* pairs = (unsigned int*)(Wh + 16384);     // 196*12288 u32 (9.6 MB)
    unsigned short* csr = (unsigned short*)pairs;          // aliases pairs (in-place)

    k_wprep<<<8, 256, 0, stream>>>(W, Wh, bcur, sums);
    k_lin<<<(N_NODES + 63) / 64, 256, 0, stream>>>(x, Wh, att_s, att_d, xlh, a_src, a_dst);
    k_binA<<<NB_A, 1024, 0, stream>>>(ei, bcur, pairs);
    k_binB<<<NBUCK, 1024, 0, stream>>>(pairs, bcur, csr, nrange);
    k_aggr6<<<AGG_NB, 256, 0, stream>>>(nrange, csr, a_src, a_dst, xlh, y);
    k_stats<<<512, DIM, 0, stream>>>(y, bias, sums);
    k_final<<<(size_t)N_NODES * DIM / 4 / 256, 256, 0, stream>>>(y, x, sums, sumsq,
                                                                 gamma, beta, bias);
}

// Round 12
// 233.236 us; speedup vs baseline: 1.2480x; 1.0277x over previous
//
#include <hip/hip_runtime.h>
#include <hip/hip_fp16.h>
#include <math.h>

#define N_NODES 50000
#define N_EDGES 1600000
#define DIM 128
#define HEADS 8
#define NEG_SLOPE 0.2f
#define BN_EPS 1e-5f

typedef _Float16 f16x8 __attribute__((ext_vector_type(8)));
typedef float f32x4 __attribute__((ext_vector_type(4)));

// ---------------------------------------------------------------------------
// CSR build constants: bucket b = dst>>8; fixed segment base b*SEGCAP.
// ---------------------------------------------------------------------------
#define NBUCK 196
#define SEGCAP 12288
#define CHUNK 8192
#define NB_A ((N_EDGES + CHUNK - 1) / CHUNK)   // 196
#define LIN_NB ((N_NODES + 127) / 128)          // 391 (8 waves x 16 nodes)
#define FUSED_NB (NB_A + LIN_NB)                // 587

// ---------------------------------------------------------------------------
// K1: heterogeneous fused kernel, 512 threads/block.
//   blocks [0, NB_A):        binA — LDS counting sort of an 8192-edge chunk
//                            by coarse bucket, coalesced segment flush.
//   blocks [NB_A, FUSED_NB): lin — xl = x @ W via MFMA 16x16x32 f16 with
//                            W swizzled fp32->fp16 into LDS per block;
//                            fused per-head attention dots.
// The two halves are data-independent; co-residency lets MFMA-heavy lin
// waves and LDS/VALU-heavy binA waves share CUs (m114 co-schedule).
// ---------------------------------------------------------------------------
struct BinAShm {
    int hist[NBUCK], excl[NBUCK], gbase[NBUCK], cnt2[NBUCK];
    int sc[256];
    unsigned int buf[CHUNK];                // 32 KB
};
struct LinShm { __half wh[16384]; };        // 32 KB

__global__ __launch_bounds__(512) void k_linbinA(
        const float* __restrict__ x, const float* __restrict__ W,
        const float* __restrict__ att_s, const float* __restrict__ att_d,
        const int* __restrict__ ei, int* __restrict__ bcur,
        unsigned int* __restrict__ pairs, __half* __restrict__ xlh,
        float* __restrict__ a_src, float* __restrict__ a_dst) {
    __shared__ union { BinAShm a; LinShm l; } sh;
    const int t = threadIdx.x;

    if (blockIdx.x < NB_A) {
        // ----- binA -----
        const int base = blockIdx.x * CHUNK;
        const int cnt = min(CHUNK, N_EDGES - base);   // multiple of 4

        for (int j = t; j < NBUCK; j += 512) { sh.a.hist[j] = 0; sh.a.cnt2[j] = 0; }
        __syncthreads();
        for (int i = t * 4; i < cnt; i += 2048) {
            const int4 dv = *(const int4*)(ei + N_EDGES + base + i);
            atomicAdd(&sh.a.hist[dv.x >> 8], 1);
            atomicAdd(&sh.a.hist[dv.y >> 8], 1);
            atomicAdd(&sh.a.hist[dv.z >> 8], 1);
            atomicAdd(&sh.a.hist[dv.w >> 8], 1);
        }
        __syncthreads();
        if (t < 256) sh.a.sc[t] = (t < NBUCK) ? sh.a.hist[t] : 0;
        __syncthreads();
        for (int d = 1; d < 256; d <<= 1) {
            int xo = 0;
            if (t < 256 && t >= d) xo = sh.a.sc[t - d];
            __syncthreads();
            if (t < 256) sh.a.sc[t] += xo;
            __syncthreads();
        }
        if (t < NBUCK) {
            sh.a.excl[t] = sh.a.sc[t] - sh.a.hist[t];
            sh.a.gbase[t] = t * SEGCAP + atomicAdd(&bcur[t], sh.a.hist[t]);
        }
        __syncthreads();
        for (int i = t * 4; i < cnt; i += 2048) {
            const int4 sv = *(const int4*)(ei + base + i);
            const int4 dv = *(const int4*)(ei + N_EDGES + base + i);
            const int ss[4] = {sv.x, sv.y, sv.z, sv.w};
            const int dd[4] = {dv.x, dv.y, dv.z, dv.w};
            #pragma unroll
            for (int k = 0; k < 4; ++k) {
                const int b = dd[k] >> 8;
                const int r = atomicAdd(&sh.a.cnt2[b], 1);
                sh.a.buf[sh.a.excl[b] + r] = (unsigned int)ss[k]
                    | ((unsigned int)(dd[k] & 255) << 16) | ((unsigned int)b << 24);
            }
        }
        __syncthreads();
        for (int i = t; i < cnt; i += 512) {
            const unsigned int u = sh.a.buf[i];
            const int b = u >> 24;
            pairs[sh.a.gbase[b] + (i - sh.a.excl[b])] = u & 0xFFFFFF;
        }
    } else {
        // ----- lin -----
        // stage W into LDS, swizzled to MFMA B-fragment order, fp16.
        // frag g=nt*4+kt: lane holds B[k=kt*32+q*8+j][n=nt*16+(lane&15)]
        for (int v = t; v < 2048; v += 512) {
            const int g = v >> 6, lane = v & 63;
            const int nt = g >> 2, kt = g & 3;
            const int q = lane >> 4, n = lane & 15;
            #pragma unroll
            for (int j = 0; j < 8; ++j)
                sh.l.wh[(size_t)(g * 64 + lane) * 8 + j] =
                    __float2half(W[(kt * 32 + q * 8 + j) * DIM + nt * 16 + n]);
        }
        __syncthreads();

        const int wave = t >> 6;
        const int lane = t & 63;
        const int q = lane >> 4, n = lane & 15;
        const int nb = ((blockIdx.x - NB_A) * 8 + wave) * 16;

        const int rowA = min(nb + n, N_NODES - 1);
        const float* xr = x + (size_t)rowA * DIM;
        f16x8 a[4];
        #pragma unroll
        for (int kt = 0; kt < 4; ++kt) {
            const float4 p0 = *(const float4*)(xr + kt * 32 + q * 8);
            const float4 p1 = *(const float4*)(xr + kt * 32 + q * 8 + 4);
            a[kt][0] = (_Float16)p0.x; a[kt][1] = (_Float16)p0.y;
            a[kt][2] = (_Float16)p0.z; a[kt][3] = (_Float16)p0.w;
            a[kt][4] = (_Float16)p1.x; a[kt][5] = (_Float16)p1.y;
            a[kt][6] = (_Float16)p1.z; a[kt][7] = (_Float16)p1.w;
        }

        f32x4 acc[8];
        #pragma unroll
        for (int nt = 0; nt < 8; ++nt) acc[nt] = (f32x4){0.f, 0.f, 0.f, 0.f};

        const f16x8* wb = (const f16x8*)sh.l.wh;
        #pragma unroll
        for (int nt = 0; nt < 8; ++nt) {
            #pragma unroll
            for (int kt = 0; kt < 4; ++kt) {
                const f16x8 b = wb[(nt * 4 + kt) * 64 + lane];
                acc[nt] = __builtin_amdgcn_mfma_f32_16x16x32_f16(a[kt], b, acc[nt], 0, 0, 0);
            }
        }

        const int r0 = nb + q * 4;
        #pragma unroll
        for (int nt = 0; nt < 8; ++nt) {
            const float as = att_s[nt * 16 + n];
            const float ad = att_d[nt * 16 + n];
            #pragma unroll
            for (int r = 0; r < 4; ++r) {
                const int row = r0 + r;
                const float v = acc[nt][r];
                float s = v * as;
                float d = v * ad;
                #pragma unroll
                for (int off = 8; off; off >>= 1) {
                    s += __shfl_xor(s, off, 16);
                    d += __shfl_xor(d, off, 16);
                }
                if (row < N_NODES) {
                    xlh[(size_t)row * DIM + nt * 16 + n] = __float2half(v);
                    if (n == 0) {
                        a_src[row * HEADS + nt] = s;
                        a_dst[row * HEADS + nt] = d;
                    }
                }
            }
        }
    }
}

// ---------------------------------------------------------------------------
// Phase B: one block per bucket; LDS counting sort by dst&255. Node segment
// starts padded to EVEN csr indices. Emits csr (ushort) in-place into pairs
// + per-node [lo,hi) ranges. Block 0 also zeroes BN accumulators.
// ---------------------------------------------------------------------------
__global__ __launch_bounds__(1024) void k_binB(const unsigned int* __restrict__ pairs,
                                               const int* __restrict__ bcur,
                                               unsigned short* __restrict__ csr,
                                               int2* __restrict__ nrange,
                                               float* __restrict__ gsums) {
    __shared__ int hist[256], eh[256], excl[256], cnt2[256];
    __shared__ int plen;
    __shared__ unsigned short out[SEGCAP];  // 24 KB
    const int t = threadIdx.x;
    const int b = blockIdx.x;
    if (b == 0 && t < 256) gsums[t] = 0.f;  // used by k_stats later
    const int lo = b * SEGCAP;              // u32 index into pairs
    const int cnt = bcur[b];

    if (t < 256) { hist[t] = 0; cnt2[t] = 0; }
    __syncthreads();
    for (int i = t; i < cnt; i += 1024)
        atomicAdd(&hist[pairs[lo + i] >> 16], 1);
    __syncthreads();
    if (t < 256) { eh[t] = (hist[t] + 1) & ~1; excl[t] = eh[t]; }
    __syncthreads();
    for (int d = 1; d < 256; d <<= 1) {
        int xo = 0;
        if (t < 256 && t >= d) xo = excl[t - d];
        __syncthreads();
        if (t < 256) excl[t] += xo;
        __syncthreads();
    }
    if (t < 256) excl[t] -= eh[t];          // exclusive padded starts (even)
    if (t == 255) plen = excl[255] + eh[255];
    __syncthreads();
    for (int i = t; i < cnt; i += 1024) {
        const unsigned int u = pairs[lo + i];
        const int dl = u >> 16;
        const int r = atomicAdd(&cnt2[dl], 1);
        out[excl[dl] + r] = (unsigned short)(u & 0xFFFF);
    }
    __syncthreads();
    const int pl = plen;                    // <= cnt + 256 <= SEGCAP
    for (int i = t; i < pl; i += 1024)
        csr[2 * lo + i] = out[i];           // pad gaps: garbage, never read
    if (t < 256) {
        const int node = (b << 8) + t;
        if (node < N_NODES) {
            int2 rg;
            rg.x = 2 * lo + excl[t];
            rg.y = rg.x + hist[t];
            nrange[node] = rg;
        }
    }
}

// ---------------------------------------------------------------------------
// K3: fused softmax + aggregation. R6's proven 66us structure, untouched:
// ONE node per wave, 12500 blocks x 4 waves, 8 independent ushort csr loads,
// no LDS, no barriers, no atomics. Writes y only.
// ---------------------------------------------------------------------------
#define AGG_NB (N_NODES / 4)   // 12500

__global__ void k_aggr6(const int2* __restrict__ nrange,
                        const unsigned short* __restrict__ csr,
                        const float* __restrict__ a_src, const float* __restrict__ a_dst,
                        const __half* __restrict__ xlh, float* __restrict__ y) {
    const int d = blockIdx.x * 4 + (threadIdx.x >> 6);
    const int lane = threadIdx.x & 63;
    const int c2 = lane << 1;
    const int h = lane >> 3;
    const int2 rg = nrange[d];
    const int lo = rg.x, hi = rg.y;
    const float ad = a_dst[d * HEADS + h];
    float acc0 = 0.f, acc1 = 0.f, dsum = 0.f;
    int i = lo;
    for (; i + 8 <= hi; i += 8) {
        int s[8];
        float e[8];
        __half2 xv[8];
        #pragma unroll
        for (int j = 0; j < 8; ++j) s[j] = csr[i + j];
        #pragma unroll
        for (int j = 0; j < 8; ++j) e[j] = a_src[s[j] * HEADS + h] + ad;
        #pragma unroll
        for (int j = 0; j < 8; ++j)
            xv[j] = *(const __half2*)(xlh + (size_t)s[j] * DIM + c2);
        #pragma unroll
        for (int j = 0; j < 8; ++j) {
            const float w = __expf(fmaxf(e[j], NEG_SLOPE * e[j]));
            const float2 f = __half22float2(xv[j]);
            acc0 = fmaf(w, f.x, acc0);
            acc1 = fmaf(w, f.y, acc1);
            dsum += w;
        }
    }
    for (; i < hi; ++i) {
        const int s = csr[i];
        const float e = a_src[s * HEADS + h] + ad;
        const __half2 xv = *(const __half2*)(xlh + (size_t)s * DIM + c2);
        const float w = __expf(fmaxf(e, NEG_SLOPE * e));
        const float2 f = __half22float2(xv);
        acc0 = fmaf(w, f.x, acc0); acc1 = fmaf(w, f.y, acc1); dsum += w;
    }
    const float inv = 1.f / (dsum + 1e-16f);
    float2 o; o.x = acc0 * inv; o.y = acc1 * inv;
    *(float2*)(y + (size_t)d * DIM + c2) = o;
}

// ---------------------------------------------------------------------------
// BN stats over h = y + bias (512 blocks x 128 threads)
// ---------------------------------------------------------------------------
__global__ void k_stats(const float* __restrict__ y, const float* __restrict__ bias,
                        float* __restrict__ gsums) {
    const int c = threadIdx.x;
    const float b = bias[c];
    float s = 0.f, ss = 0.f;
    for (int n = blockIdx.x; n < N_NODES; n += gridDim.x) {
        const float h = y[n * DIM + c] + b;
        s += h;
        ss += h * h;
    }
    atomicAdd(&gsums[c], s);
    atomicAdd(&gsums[DIM + c], ss);
}

// ---------------------------------------------------------------------------
// K4: y = x + relu((y + bias - mean) * rsqrt(var+eps) * gamma + beta)
// BN fold computed inline per thread (sums/sumsq L2-resident).
// ---------------------------------------------------------------------------
__global__ void k_final(float* __restrict__ y, const float* __restrict__ x,
                        const float* __restrict__ sums, const float* __restrict__ sumsq,
                        const float* __restrict__ gamma, const float* __restrict__ beta,
                        const float* __restrict__ bias) {
    const int q = blockIdx.x * blockDim.x + threadIdx.x;
    const int cq = q & (DIM / 4 - 1);
    const float4 sm = ((const float4*)sums)[cq];
    const float4 sq = ((const float4*)sumsq)[cq];
    const float4 gm = ((const float4*)gamma)[cq];
    const float4 bt = ((const float4*)beta)[cq];
    const float4 bs = ((const float4*)bias)[cq];
    float4 v = ((const float4*)y)[q];
    const float4 xv = ((const float4*)x)[q];
    const float inv_n = 1.f / (float)N_NODES;
#define BNC(c) { const float mean = sm.c * inv_n;                         \
                 const float var = sq.c * inv_n - mean * mean;            \
                 const float sc = rsqrtf(var + BN_EPS) * gm.c;            \
                 const float sh = bt.c + (bs.c - mean) * sc;              \
                 v.c = xv.c + fmaxf(v.c * sc + sh, 0.f); }
    BNC(x) BNC(y) BNC(z) BNC(w)
#undef BNC
    ((float4*)y)[q] = v;
}

extern "C" void kernel_launch(void* const* d_in, const int* in_sizes, int n_in,
                              void* d_out, int out_size, void* d_ws, size_t ws_size,
                              hipStream_t stream) {
    const float* x     = (const float*)d_in[0];
    const int*   ei    = (const int*)  d_in[1];
    const float* W     = (const float*)d_in[2];
    const float* att_s = (const float*)d_in[3];
    const float* att_d = (const float*)d_in[4];
    const float* bias  = (const float*)d_in[5];
    const float* gamma = (const float*)d_in[6];
    const float* beta  = (const float*)d_in[7];
    float* y = (float*)d_out;

    // workspace layout
    __half* xlh  = (__half*)d_ws;                          // 6,400,000 h (12.8 MB)
    float* a_src = (float*)(xlh + (size_t)N_NODES * DIM);  // 400,000 f
    float* a_dst = a_src + (size_t)N_NODES * HEADS;        // 400,000 f
    float* sums  = a_dst + (size_t)N_NODES * HEADS;        // 128 f
    float* sumsq = sums  + DIM;                            // 128 f
    int*   bcur  = (int*)(sumsq + DIM);                    // 256 i
    int2*  nrange = (int2*)(bcur + 256);                   // 50,000 int2
    unsigned int* pairs = (unsigned int*)(nrange + N_NODES); // 196*12288 u32 (9.6 MB)
    unsigned short* csr = (unsigned short*)pairs;          // aliases pairs (in-place)

    hipMemsetAsync(bcur, 0, 256 * sizeof(int), stream);
    k_linbinA<<<FUSED_NB, 512, 0, stream>>>(x, W, att_s, att_d, ei, bcur, pairs,
                                            xlh, a_src, a_dst);
    k_binB<<<NBUCK, 1024, 0, stream>>>(pairs, bcur, csr, nrange, sums);
    k_aggr6<<<AGG_NB, 256, 0, stream>>>(nrange, csr, a_src, a_dst, xlh, y);
    k_stats<<<512, DIM, 0, stream>>>(y, bias, sums);
    k_final<<<(size_t)N_NODES * DIM / 4 / 256, 256, 0, stream>>>(y, x, sums, sumsq,
                                                                 gamma, beta, bias);
}